// Round 1
// baseline (696.624 us; speedup 1.0000x reference)
//
#include <hip/hip_runtime.h>
#include <hip/hip_bf16.h>

#define BB 8192
#define MM 64
#define DD 256
#define NEGV -1e9f
#define PSTR 68   // part[] row stride in floats

typedef __attribute__((ext_vector_type(8))) short frag_ab;  // 8 bf16 = 4 VGPRs
typedef __attribute__((ext_vector_type(4))) float f32x4;

__device__ inline short f2bs(float f) {
    __hip_bfloat16 v = __float2bfloat16(f);
    return *reinterpret_cast<short*>(&v);
}

__device__ inline frag_ab pack8(const float4 a, const float4 b) {
    frag_ab f;
    f[0] = f2bs(a.x); f[1] = f2bs(a.y); f[2] = f2bs(a.z); f[3] = f2bs(a.w);
    f[4] = f2bs(b.x); f[5] = f2bs(b.y); f[6] = f2bs(b.z); f[7] = f2bs(b.w);
    return f;
}

// ---------------------------------------------------------------------------
// Kernel A v5: per-sample masked attention.
//   Changes vs v4:
//   - tile kept as 16x float4 FP32 in registers (64 VGPRs) instead of packed
//     bf16 -> no cvt/unpack VALU, fp32-exact phase 4.
//   - __launch_bounds__(256,4): 128-VGPR cap so all 16 row loads can be in
//     flight (v4's cap of ~80 left ~0 regs for load MLP next to the tile).
//   - masked rows still skipped (wave-uniform branch): avg mem traffic ~273MB.
// ---------------------------------------------------------------------------
__global__ __launch_bounds__(256, 4) void attn_kernel(
    const float* __restrict__ h, const float* __restrict__ mem,
    const int* __restrict__ len, float* __restrict__ r_out)
{
    __shared__ float part[MM * PSTR];              // 17.4 KB [m][lane]
    __shared__ float score_s[MM];
    __shared__ __align__(16) float attn_s[MM];
    __shared__ __align__(16) float rpart[4 * DD];  // 4 KB [wave][d]

    const int b    = blockIdx.x;
    const int t    = threadIdx.x;
    const int lane = t & 63;
    const int wave = t >> 6;
    const int L    = len[b];
    // rows this wave actually needs (wave-uniform)
    const int nrows = min(16, max(0, L - wave * 16));

    const float4 hv = *reinterpret_cast<const float4*>(h + (size_t)b * DD + 4 * lane);
    const float* mbase = mem + (size_t)b * MM * DD + (size_t)(wave * 16) * DD + 4 * lane;

    // ---- phase 1: batch-issue loads for all valid rows (coalesced 1KB/row),
    //      keep raw fp32 tile in registers; zeros for masked rows.
    float4 v[16];
    #pragma unroll
    for (int i = 0; i < 16; ++i) v[i] = float4{0.f, 0.f, 0.f, 0.f};
    #pragma unroll
    for (int i = 0; i < 16; ++i) {
        if (i < nrows)     // wave-uniform; no dependent use inside -> loads pipeline
            v[i] = *reinterpret_cast<const float4*>(mbase + i * DD);
    }
    #pragma unroll
    for (int i = 0; i < 16; ++i)
        part[(wave * 16 + i) * PSTR + lane] =
            v[i].x * hv.x + v[i].y * hv.y + v[i].z * hv.z + v[i].w * hv.w;
    __syncthreads();

    // ---- phase 2: finish dots: thread -> row m=t>>2, chunk c=t&3
    {
        const int m = t >> 2, c = t & 3;
        const float4* pr = reinterpret_cast<const float4*>(part + m * PSTR + c * 16);
        const float4 s0 = pr[0], s1 = pr[1], s2 = pr[2], s3 = pr[3];
        float s = (s0.x + s0.y + s0.z + s0.w) + (s1.x + s1.y + s1.z + s1.w)
                + (s2.x + s2.y + s2.z + s2.w) + (s3.x + s3.y + s3.z + s3.w);
        s += __shfl_xor(s, 1, 64);
        s += __shfl_xor(s, 2, 64);
        if (c == 0) score_s[m] = (m < L) ? s : NEGV;
    }
    __syncthreads();

    // ---- phase 3: masked softmax over 64 scores (wave 0).
    // L==0: attn uniform but tile==0 -> r garbage-free 0; gate passes h anyway
    if (t < 64) {
        const float s = score_s[t];
        float mx = s;
        #pragma unroll
        for (int off = 32; off > 0; off >>= 1)
            mx = fmaxf(mx, __shfl_xor(mx, off, 64));
        const float e = __expf(s - mx);
        float den = e;
        #pragma unroll
        for (int off = 32; off > 0; off >>= 1)
            den += __shfl_xor(den, off, 64);
        attn_s[t] = e / den;
    }
    __syncthreads();

    // ---- phase 4: r partials from the fp32 register tile
    float4 rp = {0.f, 0.f, 0.f, 0.f};
    if (nrows > 0) {
        #pragma unroll
        for (int ic = 0; ic < 4; ++ic) {
            const float4 aw = *reinterpret_cast<const float4*>(attn_s + wave * 16 + 4 * ic);
            const float a[4] = {aw.x, aw.y, aw.z, aw.w};
            #pragma unroll
            for (int k = 0; k < 4; ++k) {
                const int i = 4 * ic + k;
                rp.x += a[k] * v[i].x;
                rp.y += a[k] * v[i].y;
                rp.z += a[k] * v[i].z;
                rp.w += a[k] * v[i].w;
            }
        }
    }
    *reinterpret_cast<float4*>(rpart + wave * DD + 4 * lane) = rp;
    __syncthreads();

    // ---- phase 5: cross-wave sum + store (coalesced)
    const float r = rpart[t] + rpart[DD + t] + rpart[2 * DD + t] + rpart[3 * DD + t];
    r_out[(size_t)b * DD + t] = r;
}

// ---------------------------------------------------------------------------
// Kernel B v4: gating GEMMs + blend, bf16 MFMA 16x16x32.
//   Changes vs v3: NO LDS, NO barriers. Each wave loads its MFMA fragments
//   directly from global (W is 0.5MB total and h/r tiles are L2-hot from the
//   4x dcol re-reads), converts to bf16 in-register, runs a fully unrolled
//   barrier-free K-loop. v3 had 2 full vmcnt(0)+barrier drains per 8 MFMAs
//   at only 2 blocks/CU -> pure lockstep latency; this removes all of it.
// ---------------------------------------------------------------------------
__global__ __launch_bounds__(256, 2) void gate_kernel(
    const float* __restrict__ h, const float* __restrict__ r,
    const int* __restrict__ len,
    const float* __restrict__ Wg_w, const float* __restrict__ Wg_b,
    const float* __restrict__ Ug_w, const float* __restrict__ Ug_b,
    const float* __restrict__ b_g, float* __restrict__ out)
{
    const int t    = threadIdx.x;
    const int lane = t & 63;
    const int wave = t >> 6;
    const int brow0 = blockIdx.x * 64;
    const int dcol0 = blockIdx.y * 64;

    const int am = lane & 15;         // fragment row (A) / col (B) within 16
    const int kc = (lane >> 4) * 8;   // k-octet within the 32-wide K step

    // A-side: this wave's 16 h/r rows
    const float* hp = h + (size_t)(brow0 + wave * 16 + am) * DD + kc;
    const float* rp = r + (size_t)(brow0 + wave * 16 + am) * DD + kc;
    // B-side: W^T rows (= W output columns), ct*16*DD added per tile
    const float* gp = Wg_w + (size_t)(dcol0 + am) * DD + kc;
    const float* up = Ug_w + (size_t)(dcol0 + am) * DD + kc;

    const f32x4 zero = {0.f, 0.f, 0.f, 0.f};
    f32x4 acc[4];
    #pragma unroll
    for (int ct = 0; ct < 4; ++ct) acc[ct] = zero;

    #pragma unroll
    for (int k0 = 0; k0 < DD; k0 += 32) {
        const float4 h0 = *reinterpret_cast<const float4*>(hp + k0);
        const float4 h1 = *reinterpret_cast<const float4*>(hp + k0 + 4);
        const float4 r0 = *reinterpret_cast<const float4*>(rp + k0);
        const float4 r1 = *reinterpret_cast<const float4*>(rp + k0 + 4);
        const frag_ab afh = pack8(h0, h1);
        const frag_ab afr = pack8(r0, r1);
        #pragma unroll
        for (int ct = 0; ct < 4; ++ct) {
            const float4 g0 = *reinterpret_cast<const float4*>(gp + (size_t)ct * 16 * DD + k0);
            const float4 g1 = *reinterpret_cast<const float4*>(gp + (size_t)ct * 16 * DD + k0 + 4);
            const float4 u0 = *reinterpret_cast<const float4*>(up + (size_t)ct * 16 * DD + k0);
            const float4 u1 = *reinterpret_cast<const float4*>(up + (size_t)ct * 16 * DD + k0 + 4);
            const frag_ab wfg = pack8(g0, g1);
            const frag_ab wfu = pack8(u0, u1);
            acc[ct] = __builtin_amdgcn_mfma_f32_16x16x32_bf16(afh, wfg, acc[ct], 0, 0, 0);
            acc[ct] = __builtin_amdgcn_mfma_f32_16x16x32_bf16(afr, wfu, acc[ct], 0, 0, 0);
        }
    }

    // epilogue: bias + sigmoid + blend + empty-memory passthrough
    // C/D layout: col = lane&15, row = (lane>>4)*4 + reg
    float bias_v[4];
    #pragma unroll
    for (int ct = 0; ct < 4; ++ct) {
        const int d = dcol0 + ct * 16 + am;
        bias_v[ct] = Wg_b[d] + Ug_b[d] + b_g[d];
    }
    const int rbase = brow0 + wave * 16 + (lane >> 4) * 4;
    #pragma unroll
    for (int i = 0; i < 4; ++i) {
        const int bb = rbase + i;
        const int lb = len[bb];
        #pragma unroll
        for (int ct = 0; ct < 4; ++ct) {
            const int d = dcol0 + ct * 16 + am;
            const float x = acc[ct][i] + bias_v[ct];
            const float g = 1.f / (1.f + __expf(-x));
            const size_t idx = (size_t)bb * DD + d;
            const float rv = r[idx];
            const float hvv = h[idx];
            out[idx] = (lb > 0) ? (hvv + g * (rv - hvv)) : hvv;
        }
    }
}

extern "C" void kernel_launch(void* const* d_in, const int* in_sizes, int n_in,
                              void* d_out, int out_size, void* d_ws, size_t ws_size,
                              hipStream_t stream) {
    const float* h    = (const float*)d_in[0];
    const float* mem  = (const float*)d_in[1];
    const int*   len  = (const int*)d_in[2];
    const float* Wg_w = (const float*)d_in[3];
    const float* Wg_b = (const float*)d_in[4];
    const float* Ug_w = (const float*)d_in[5];
    const float* Ug_b = (const float*)d_in[6];
    const float* b_g  = (const float*)d_in[7];
    float* out  = (float*)d_out;
    float* r_ws = (float*)d_ws;   // B*D*4 = 8 MiB scratch for r

    attn_kernel<<<BB, 256, 0, stream>>>(h, mem, len, r_ws);
    gate_kernel<<<dim3(BB / 64, DD / 64), 256, 0, stream>>>(
        h, r_ws, len, Wg_w, Wg_b, Ug_w, Ug_b, b_g, out);
}